// Round 5
// baseline (1544.292 us; speedup 1.0000x reference)
//
#include <hip/hip_runtime.h>
#include <hip/hip_bf16.h>
#include <math.h>

// Problem constants (pinned by reference)
constexpr int BB = 4;
constexpr int TT = 512;
constexpr int DD = 2048;
constexpr int HH = 6;
constexpr int KK = 256;   // head_k_dim
constexpr int VV = 512;   // head_v_dim
constexpr int NHOUSE = 2;
constexpr int MM = BB * TT;          // 2048 rows
constexpr int KEY_DIM = HH * KK;     // 1536
constexpr int VAL_DIM = HH * VV;     // 3072

// qkv fp32 buffer: row stride 10752, col ranges q[0,1536) k[1536,4608) v[4608,10752)
constexpr int QKV_ST = 10752;
constexpr int QOFF = 0;
constexpr int KOFF = 1536;
constexpr int VOFF = 4608;

// ---- workspace layout (FLOAT units), constexpr to avoid literal mistakes ----
constexpr size_t SZ_QKV  = (size_t)MM * QKV_ST;          // 22,020,096
constexpr size_t SZ_GATE = (size_t)MM * VAL_DIM / 2;     //  3,145,728 (f16)
constexpr size_t SZ_BETA = (size_t)MM * NHOUSE * HH;     //     24,576
constexpr size_t SZ_GEXP = (size_t)MM * HH;              //     12,288
constexpr size_t SZ_X16  = (size_t)MM * DD / 2;          //  2,097,152 (f16)
constexpr size_t SZ_W16  = (size_t)3072 * DD / 2;        //  3,145,728 (f16, max chunk)
constexpr size_t SZ_OMID = (size_t)MM * VAL_DIM;         //  6,291,456

constexpr size_t OFF_QKV  = 0;
constexpr size_t OFF_GATE = OFF_QKV + SZ_QKV;
constexpr size_t OFF_BETA = OFF_GATE + SZ_GATE;
constexpr size_t OFF_GEXP = OFF_BETA + SZ_BETA;
constexpr size_t OFF_X16  = OFF_GEXP + SZ_GEXP;
constexpr size_t OFF_W16  = OFF_X16 + SZ_X16;
constexpr size_t OFF_OMID = OFF_X16;                     // overlays x16+wf16
constexpr size_t WS_PEAK  = OFF_OMID + SZ_OMID;          // 31,494,144 fl = 126.0 MB
static_assert(OFF_OMID + SZ_OMID >= OFF_W16 + SZ_W16, "omid covers w16");
static_assert(WS_PEAK <= 34600000, "stay under round-1-proven 138.5 MB");
constexpr size_t OFF_O2   = 0;                           // overlays dead qkv
constexpr size_t OFF_WO16 = SZ_GATE;
static_assert(OFF_WO16 + (size_t)DD * VAL_DIM / 2 <= SZ_QKV, "o2+wo16 fit in dead qkv");

__device__ __forceinline__ float rsqrt_nr(float x) {
  float r = rsqrtf(x);
  return r * (1.5f - 0.5f * x * r * r);
}
__device__ __forceinline__ float sigmoidf_(float x) {
  return 1.f / (1.f + expf(-x));
}
__device__ __forceinline__ short f2h(float f) {
  _Float16 h = (_Float16)f;
  short s;
  __builtin_memcpy(&s, &h, 2);
  return s;
}

typedef __attribute__((ext_vector_type(8))) _Float16 f16x8;
typedef __attribute__((ext_vector_type(4))) float f32x4;

__device__ __forceinline__ void gload_lds16(const short* g, short* l) {
  __builtin_amdgcn_global_load_lds(
      (const __attribute__((address_space(1))) void*)g,
      (__attribute__((address_space(3))) void*)l, 16, 0, 0);
}

// ---------------------------------------------------------------------------
// fp32 -> fp16 flat conversion, 4 elems/thread.
// ---------------------------------------------------------------------------
__global__ __launch_bounds__(256) void cvt_f16(const float* __restrict__ src,
                                               short* __restrict__ dst, int n) {
  int i = (blockIdx.x * 256 + threadIdx.x) << 2;
  if (i >= n) return;
  float4 v = *(const float4*)(src + i);
  short4 r;
  r.x = f2h(v.x); r.y = f2h(v.y); r.z = f2h(v.z); r.w = f2h(v.w);
  *(short4*)(dst + i) = r;
}

// ---------------------------------------------------------------------------
// C = act(A * B^T). modes: 0 = f32 out, 1 = f32 out + silu, 2 = f16 out,
// 3 = f32 out + silu + *K^-0.5 (q projection: folds the query scale).
// m97-verified structure (see round 4).
// ---------------------------------------------------------------------------
__global__ __launch_bounds__(256) void gemm_f16(const short* __restrict__ A,
                                                const short* __restrict__ B,
                                                void* __restrict__ Cout,
                                                int ldc, int Kd, int lda, int ldb,
                                                int mode) {
  __shared__ __align__(16) short lds[8192];  // A tile 128x32 | B tile 128x32
  const int tid = threadIdx.x;
  const int lane = tid & 63;
  const int w = tid >> 6;
  const int m0 = blockIdx.x * 128;
  const int n0 = blockIdx.y * 128;

  const int sr = w * 32 + (lane >> 2);
  const int sc = (lane & 3) << 3;
  const short* ga1 = A + (size_t)(m0 + sr) * lda + sc;
  const short* ga2 = ga1 + (size_t)16 * lda;
  const short* gb1 = B + (size_t)(n0 + sr) * ldb + sc;
  const short* gb2 = gb1 + (size_t)16 * ldb;
  short* la1 = &lds[(size_t)w * 1024];
  short* la2 = la1 + 512;
  short* lb1 = &lds[4096 + (size_t)w * 1024];
  short* lb2 = lb1 + 512;

  const int fr = lane & 15;
  const int kg = lane >> 4;
  const int wmB = (w & 1) * 64;
  const int wnB = (w >> 1) * 64;
  int aoff[4], boff[4];
#pragma unroll
  for (int i = 0; i < 4; ++i) {
    aoff[i] = (wmB + i * 16 + fr) * 32 + kg * 8;
    boff[i] = 4096 + (wnB + i * 16 + fr) * 32 + kg * 8;
  }

  f32x4 acc[4][4];
#pragma unroll
  for (int i = 0; i < 4; ++i)
#pragma unroll
    for (int j = 0; j < 4; ++j) acc[i][j] = (f32x4){0.f, 0.f, 0.f, 0.f};

  const int nk = Kd >> 5;
  for (int kt = 0; kt < nk; ++kt) {
    const int ko = kt << 5;
    __syncthreads();
    gload_lds16(ga1 + ko, la1);
    gload_lds16(ga2 + ko, la2);
    gload_lds16(gb1 + ko, lb1);
    gload_lds16(gb2 + ko, lb2);
    __syncthreads();
    f16x8 af[4], bf[4];
#pragma unroll
    for (int i = 0; i < 4; ++i) af[i] = *(const f16x8*)(lds + aoff[i]);
#pragma unroll
    for (int j = 0; j < 4; ++j) bf[j] = *(const f16x8*)(lds + boff[j]);
#pragma unroll
    for (int i = 0; i < 4; ++i)
#pragma unroll
      for (int j = 0; j < 4; ++j)
        acc[i][j] = __builtin_amdgcn_mfma_f32_16x16x32_f16(af[i], bf[j], acc[i][j], 0, 0, 0);
  }

#pragma unroll
  for (int i = 0; i < 4; ++i) {
    const int row = m0 + wmB + i * 16 + kg * 4;
#pragma unroll
    for (int j = 0; j < 4; ++j) {
      const int col = n0 + wnB + j * 16 + fr;
#pragma unroll
      for (int e = 0; e < 4; ++e) {
        float v = acc[i][j][e];
        if (mode == 1 || mode == 3) v = v / (1.f + expf(-v));  // silu
        if (mode == 3) v *= 0.0625f;                            // K^-0.5
        if (mode == 2) {
          ((_Float16*)Cout)[(size_t)(row + e) * ldc + col] = (_Float16)v;
        } else {
          ((float*)Cout)[(size_t)(row + e) * ldc + col] = v;
        }
      }
    }
  }
}

// ---------------------------------------------------------------------------
// In-place L2-normalization of each k head-row (256 floats) in the qkv
// buffer: kn = k / max(||k||, 1e-12). One wave per row; 4 rows per block.
// rows = MM*NH*HH = 24576.
// ---------------------------------------------------------------------------
__global__ __launch_bounds__(256) void prep_kn(float* __restrict__ qkv) {
  const int row = blockIdx.x * 4 + (threadIdx.x >> 6);
  const int lane = threadIdx.x & 63;
  const int m = row / (NHOUSE * HH);
  const int rem = row % (NHOUSE * HH);
  const int j = rem / HH;
  const int hh = rem % HH;
  float* p = qkv + (size_t)m * QKV_ST + KOFF + j * KEY_DIM + hh * KK;
  float4 v = ((float4*)p)[lane];
  float ss = v.x * v.x + v.y * v.y + v.z * v.z + v.w * v.w;
#pragma unroll
  for (int off = 32; off; off >>= 1) ss += __shfl_xor(ss, off);
  float inv = rsqrt_nr(fmaxf(ss, 1e-24f));  // == 1/max(||k||,1e-12)
  v.x *= inv; v.y *= inv; v.z *= inv; v.w *= inv;
  ((float4*)p)[lane] = v;
}

// ---------------------------------------------------------------------------
// Small projections (fp32): y = x @ [Wb;Wa]^T per row (18 outs) ->
// beta = 2*sigmoid, gexp = exp(-exp(A_log)*softplus(y+dt_bias)).
// ---------------------------------------------------------------------------
__global__ __launch_bounds__(256) void small_proj(const float* __restrict__ x,
                                                  const float* __restrict__ Wb,
                                                  const float* __restrict__ Wa,
                                                  const float* __restrict__ A_log,
                                                  const float* __restrict__ dt_bias,
                                                  float* __restrict__ beta_out,
                                                  float* __restrict__ gexp_out) {
  const int m = blockIdx.x;
  const int tid = threadIdx.x;
  const int lane = tid & 63;
  const int wv = tid >> 6;
  __shared__ float xs[DD];
  __shared__ float ybuf[18];
#pragma unroll
  for (int i = 0; i < DD / 256; ++i) xs[tid + 256 * i] = x[(size_t)m * DD + tid + 256 * i];
  __syncthreads();
  for (int n = wv; n < 18; n += 4) {
    const float* wrow = (n < 12) ? (Wb + (size_t)n * DD) : (Wa + (size_t)(n - 12) * DD);
    float p = 0.f;
#pragma unroll
    for (int i = 0; i < DD / 64; ++i) p = fmaf(xs[lane + 64 * i], wrow[lane + 64 * i], p);
#pragma unroll
    for (int off = 32; off; off >>= 1) p += __shfl_xor(p, off);
    if (lane == 0) ybuf[n] = p;
  }
  __syncthreads();
  if (tid < 12) {
    beta_out[(size_t)m * 12 + tid] = 2.f * sigmoidf_(ybuf[tid]);
  } else if (tid < 18) {
    int hh = tid - 12;
    float z = ybuf[tid] + dt_bias[hh];
    float sp = fmaxf(z, 0.f) + log1pf(expf(-fabsf(z)));
    float g = -expf(A_log[hh]) * sp;
    gexp_out[(size_t)m * HH + hh] = expf(g);
  }
}

// ---------------------------------------------------------------------------
// Sequential delta-rule recurrence (fp32), v2.
// Inputs pre-processed: k rows L2-normalized (prep_kn), q pre-scaled (GEMM
// mode 3) -> no per-step norms. Partition: kq = tid&31 owns k[kq*8..+8),
// vl = tid>>5 owns one of 8 v-cols. Grid = BB*HH*(VV/8) = 1536 blocks
// (6 blocks/CU, 24 waves/CU). State 8 regs/thread. Double-buffered LDS,
// one barrier/step, next step's globals prefetched before compute.
// ---------------------------------------------------------------------------
__global__ __launch_bounds__(256) void recurrence(const float* __restrict__ QKV,
                                                  const float* __restrict__ beta,
                                                  const float* __restrict__ gexp,
                                                  float* __restrict__ o) {
  constexpr int CH = VV / 8;  // 64 v-chunks
  const int bid = blockIdx.x;
  const int b = bid / (HH * CH);
  const int rem = bid % (HH * CH);
  const int hh = rem / CH;
  const int v0 = (rem % CH) * 8;
  const int tid = threadIdx.x;
  const int kq = tid & 31;                 // k-segment (8 floats)
  const int vl = tid >> 5;                 // v column 0..7
  const int pidx = tid + 4 * (tid >> 4);   // padded staging index (20-stride)
  const int roff = (kq >> 1) * 20 + (kq & 1) * 8;  // padded read offset

  __shared__ __align__(16) float ks[2][2][320];
  __shared__ __align__(16) float qs[2][320];
  __shared__ float vs[2][2][8];
  __shared__ float bs[2][2];
  __shared__ float gs[2];

  float hreg[8];
#pragma unroll
  for (int i = 0; i < 8; ++i) hreg[i] = 0.f;

  // prologue: stage t=0 into buf 0
  {
    const int m = b * TT;
    const float* prow = QKV + (size_t)m * QKV_ST;
    float rq = prow[QOFF + hh * KK + tid];
    float rk0 = prow[KOFF + hh * KK + tid];
    float rk1 = prow[KOFF + KEY_DIM + hh * KK + tid];
    ks[0][0][pidx] = rk0; ks[0][1][pidx] = rk1; qs[0][pidx] = rq;
    if (tid < 16) vs[0][tid >> 3][tid & 7] =
        prow[VOFF + (tid >> 3) * VAL_DIM + hh * VV + v0 + (tid & 7)];
    if (tid >= 16 && tid < 18) bs[0][tid - 16] = beta[(size_t)(m * NHOUSE + (tid - 16)) * HH + hh];
    if (tid == 18) gs[0] = gexp[(size_t)m * HH + hh];
  }
  __syncthreads();

#pragma unroll 2
  for (int t = 0; t < TT; ++t) {
    const int buf = t & 1;
    const int nb = buf ^ 1;
    const int tnx = (t + 1 < TT) ? (t + 1) : t;
    const int mn = b * TT + tnx;
    const float* prow = QKV + (size_t)mn * QKV_ST;

    // ---- prefetch next step's globals ----
    float rq = prow[QOFF + hh * KK + tid];
    float rk0 = prow[KOFF + hh * KK + tid];
    float rk1 = prow[KOFF + KEY_DIM + hh * KK + tid];
    float rv = 0.f, rb = 0.f, rg = 0.f;
    if (tid < 16) rv = prow[VOFF + (tid >> 3) * VAL_DIM + hh * VV + v0 + (tid & 7)];
    if (tid >= 16 && tid < 18) rb = beta[(size_t)(mn * NHOUSE + (tid - 16)) * HH + hh];
    if (tid == 18) rg = gexp[(size_t)mn * HH + hh];

    // ---- compute step t ----
    const float ge = gs[buf];
#pragma unroll
    for (int i = 0; i < 8; ++i) hreg[i] *= ge;

#pragma unroll
    for (int j = 0; j < 2; ++j) {
      float4 x0 = *(const float4*)&ks[buf][j][roff];
      float4 x1 = *(const float4*)&ks[buf][j][roff + 4];
      float kn[8] = {x0.x, x0.y, x0.z, x0.w, x1.x, x1.y, x1.z, x1.w};
      float p = 0.f;
#pragma unroll
      for (int i = 0; i < 8; ++i) p = fmaf(hreg[i], kn[i], p);
      p += __shfl_xor(p, 1); p += __shfl_xor(p, 2); p += __shfl_xor(p, 4);
      p += __shfl_xor(p, 8); p += __shfl_xor(p, 16);
      const float wgt = bs[buf][j] * (vs[buf][j][vl] - p);
#pragma unroll
      for (int i = 0; i < 8; ++i) hreg[i] = fmaf(wgt, kn[i], hreg[i]);
    }

    {
      float4 x0 = *(const float4*)&qs[buf][roff];
      float4 x1 = *(const float4*)&qs[buf][roff + 4];
      float qv[8] = {x0.x, x0.y, x0.z, x0.w, x1.x, x1.y, x1.z, x1.w};
      float p = 0.f;
#pragma unroll
      for (int i = 0; i < 8; ++i) p = fmaf(hreg[i], qv[i], p);
      p += __shfl_xor(p, 1); p += __shfl_xor(p, 2); p += __shfl_xor(p, 4);
      p += __shfl_xor(p, 8); p += __shfl_xor(p, 16);
      if (kq == 0) o[(size_t)((b * TT + t) * HH + hh) * VV + v0 + vl] = p;
    }

    // ---- stage t+1 into the other buffer ----
    ks[nb][0][pidx] = rk0; ks[nb][1][pidx] = rk1; qs[nb][pidx] = rq;
    if (tid < 16) vs[nb][tid >> 3][tid & 7] = rv;
    if (tid >= 16 && tid < 18) bs[nb][tid - 16] = rb;
    if (tid == 18) gs[nb] = rg;
    __syncthreads();
  }
}

// ---------------------------------------------------------------------------
// Gated RMSNorm. Reads o_mid fp32 + gate f16; writes o2 f16.
// ---------------------------------------------------------------------------
__global__ __launch_bounds__(256) void rms_gate_kernel(const float* __restrict__ o,
                                                       const short* __restrict__ gate16,
                                                       const float* __restrict__ wn,
                                                       short* __restrict__ o2) {
  const int row = blockIdx.x;            // m*H + h
  const int m = row / HH;
  const int hh = row - m * HH;
  const int tid = threadIdx.x;
  const float* op = o + (size_t)row * VV;
  const _Float16* gp = (const _Float16*)gate16 + (size_t)m * VAL_DIM + hh * VV;
  float a0 = op[tid], a1 = op[tid + 256];
  float ss = a0 * a0 + a1 * a1;
#pragma unroll
  for (int off = 32; off; off >>= 1) ss += __shfl_xor(ss, off);
  __shared__ float red[4];
  const int lane = tid & 63, wv = tid >> 6;
  if (lane == 0) red[wv] = ss;
  __syncthreads();
  float tot = red[0] + red[1] + red[2] + red[3];
  float inv = rsqrt_nr(tot * (1.f / (float)VV) + 1e-5f);
  float r0 = a0 * inv * wn[tid] * sigmoidf_((float)gp[tid]);
  float r1 = a1 * inv * wn[tid + 256] * sigmoidf_((float)gp[tid + 256]);
  _Float16* dst = (_Float16*)o2 + (size_t)m * VAL_DIM + hh * VV;
  dst[tid] = (_Float16)r0;
  dst[tid + 256] = (_Float16)r1;
}

// ---------------------------------------------------------------------------
extern "C" void kernel_launch(void* const* d_in, const int* in_sizes, int n_in,
                              void* d_out, int out_size, void* d_ws, size_t ws_size,
                              hipStream_t stream) {
  (void)in_sizes; (void)n_in; (void)out_size; (void)ws_size;
  const float* x       = (const float*)d_in[0];
  const float* Wq      = (const float*)d_in[1];
  const float* Wk      = (const float*)d_in[2];
  const float* Wv      = (const float*)d_in[3];
  const float* Wb      = (const float*)d_in[4];
  const float* Wa      = (const float*)d_in[5];
  const float* A_log   = (const float*)d_in[6];
  const float* dt_bias = (const float*)d_in[7];
  const float* Wg      = (const float*)d_in[8];
  const float* Wo      = (const float*)d_in[9];
  const float* onw     = (const float*)d_in[10];
  float* out = (float*)d_out;
  float* ws = (float*)d_ws;

  float* qkv    = ws + OFF_QKV;
  short* gate16 = (short*)(ws + OFF_GATE);
  float* beta_w = ws + OFF_BETA;
  float* gexp_w = ws + OFF_GEXP;
  short* x16    = (short*)(ws + OFF_X16);
  short* wf16   = (short*)(ws + OFF_W16);
  float* o_mid  = ws + OFF_OMID;          // overlays x16+wf16 after GEMMs
  short* o2     = (short*)(ws + OFF_O2);  // overlays dead qkv after recurrence
  short* wo16   = (short*)(ws + OFF_WO16);

  // 1. conversions + small projections
  cvt_f16<<<4096, 256, 0, stream>>>(x, x16, MM * DD);
  small_proj<<<MM, 256, 0, stream>>>(x, Wb, Wa, A_log, dt_bias, beta_w, gexp_w);

  // 2. projection GEMMs (f16 inputs, fp32 out), sequential weight chunks.
  //    q: silu + K^-0.5 scale folded (mode 3)
  cvt_f16<<<3072, 256, 0, stream>>>(Wq, wf16, KEY_DIM * DD);
  gemm_f16<<<dim3(MM / 128, KEY_DIM / 128), 256, 0, stream>>>(
      x16, wf16, qkv + QOFF, QKV_ST, DD, DD, DD, 3);
  //    k: silu, then in-place L2 normalize per head-row
  cvt_f16<<<6144, 256, 0, stream>>>(Wk, wf16, KEY_DIM * NHOUSE * DD);
  gemm_f16<<<dim3(MM / 128, (KEY_DIM * NHOUSE) / 128), 256, 0, stream>>>(
      x16, wf16, qkv + KOFF, QKV_ST, DD, DD, DD, 1);
  prep_kn<<<MM * NHOUSE * HH / 4, 256, 0, stream>>>(qkv);
  //    v halves: silu
  cvt_f16<<<6144, 256, 0, stream>>>(Wv, wf16, VAL_DIM * DD);
  gemm_f16<<<dim3(MM / 128, VAL_DIM / 128), 256, 0, stream>>>(
      x16, wf16, qkv + VOFF, QKV_ST, DD, DD, DD, 1);
  cvt_f16<<<6144, 256, 0, stream>>>(Wv + (size_t)VAL_DIM * DD, wf16, VAL_DIM * DD);
  gemm_f16<<<dim3(MM / 128, VAL_DIM / 128), 256, 0, stream>>>(
      x16, wf16, qkv + VOFF + VAL_DIM, QKV_ST, DD, DD, DD, 1);
  //    gate: f16 out, no act
  cvt_f16<<<6144, 256, 0, stream>>>(Wg, wf16, VAL_DIM * DD);
  gemm_f16<<<dim3(MM / 128, VAL_DIM / 128), 256, 0, stream>>>(
      x16, wf16, gate16, VAL_DIM, DD, DD, DD, 2);

  // 3. sequential recurrence (fp32, v2: 1536 blocks)
  recurrence<<<BB * HH * (VV / 8), 256, 0, stream>>>(qkv, beta_w, gexp_w, o_mid);

  // 4. gated RMSNorm -> o2 f16 ; Wo -> f16
  rms_gate_kernel<<<MM * HH, 256, 0, stream>>>(o_mid, gate16, onw, o2);
  cvt_f16<<<6144, 256, 0, stream>>>(Wo, wo16, DD * VAL_DIM);

  // 5. output GEMM (f16 in, f32 out to d_out)
  gemm_f16<<<dim3(MM / 128, DD / 128), 256, 0, stream>>>(
      o2, wo16, out, DD, VAL_DIM, VAL_DIM, VAL_DIM, 0);
}

// Round 6
// 1165.764 us; speedup vs baseline: 1.3247x; 1.3247x over previous
//
#include <hip/hip_runtime.h>
#include <hip/hip_bf16.h>
#include <math.h>

// Problem constants (pinned by reference)
constexpr int BB = 4;
constexpr int TT = 512;
constexpr int DD = 2048;
constexpr int HH = 6;
constexpr int KK = 256;   // head_k_dim
constexpr int VV = 512;   // head_v_dim
constexpr int NHOUSE = 2;
constexpr int MM = BB * TT;          // 2048 rows
constexpr int KEY_DIM = HH * KK;     // 1536
constexpr int VAL_DIM = HH * VV;     // 3072

// qkv fp32 buffer: row stride 10752, col ranges q[0,1536) k[1536,4608) v[4608,10752)
constexpr int QKV_ST = 10752;
constexpr int QOFF = 0;
constexpr int KOFF = 1536;
constexpr int VOFF = 4608;

// ---- workspace layout (FLOAT units) ----
constexpr size_t SZ_QKV  = (size_t)MM * QKV_ST;          // 22,020,096
constexpr size_t SZ_GATE = (size_t)MM * VAL_DIM / 2;     //  3,145,728 (f16)
constexpr size_t SZ_BETA = (size_t)MM * NHOUSE * HH;     //     24,576
constexpr size_t SZ_GEXP = (size_t)MM * HH;              //     12,288
constexpr size_t SZ_X16  = (size_t)MM * DD / 2;          //  2,097,152 (f16)
constexpr size_t SZ_W16  = (size_t)3072 * DD / 2;        //  3,145,728 (f16, max chunk)
constexpr size_t SZ_OMID = (size_t)MM * VAL_DIM;         //  6,291,456

constexpr size_t OFF_QKV  = 0;
constexpr size_t OFF_GATE = OFF_QKV + SZ_QKV;
constexpr size_t OFF_BETA = OFF_GATE + SZ_GATE;
constexpr size_t OFF_GEXP = OFF_BETA + SZ_BETA;
constexpr size_t OFF_X16  = OFF_GEXP + SZ_GEXP;
constexpr size_t OFF_W16  = OFF_X16 + SZ_X16;
constexpr size_t OFF_OMID = OFF_X16;                     // overlays x16+wf16
constexpr size_t WS_PEAK  = OFF_OMID + SZ_OMID;          // 31,494,144 fl = 126.0 MB
static_assert(OFF_OMID + SZ_OMID >= OFF_W16 + SZ_W16, "omid covers w16");
static_assert(WS_PEAK <= 34600000, "stay under round-1-proven 138.5 MB");
constexpr size_t OFF_O2   = 0;                           // overlays dead qkv
constexpr size_t OFF_WO16 = SZ_GATE;
static_assert(OFF_WO16 + (size_t)DD * VAL_DIM / 2 <= SZ_QKV, "o2+wo16 fit in dead qkv");

__device__ __forceinline__ float rsqrt_nr(float x) {
  float r = rsqrtf(x);
  return r * (1.5f - 0.5f * x * r * r);
}
__device__ __forceinline__ float sigmoidf_(float x) {
  return 1.f / (1.f + expf(-x));
}
__device__ __forceinline__ short f2h(float f) {
  _Float16 h = (_Float16)f;
  short s;
  __builtin_memcpy(&s, &h, 2);
  return s;
}

typedef __attribute__((ext_vector_type(8))) _Float16 f16x8;
typedef __attribute__((ext_vector_type(4))) float f32x4;

__device__ __forceinline__ void gload_lds16(const short* g, short* l) {
  __builtin_amdgcn_global_load_lds(
      (const __attribute__((address_space(1))) void*)g,
      (__attribute__((address_space(3))) void*)l, 16, 0, 0);
}

// ---------------------------------------------------------------------------
// fp32 -> fp16 flat conversion, 4 elems/thread.
// ---------------------------------------------------------------------------
__global__ __launch_bounds__(256) void cvt_f16(const float* __restrict__ src,
                                               short* __restrict__ dst, int n) {
  int i = (blockIdx.x * 256 + threadIdx.x) << 2;
  if (i >= n) return;
  float4 v = *(const float4*)(src + i);
  short4 r;
  r.x = f2h(v.x); r.y = f2h(v.y); r.z = f2h(v.z); r.w = f2h(v.w);
  *(short4*)(dst + i) = r;
}

// ---------------------------------------------------------------------------
// C = act(A * B^T). modes: 0 = f32 out, 1 = f32 out + silu, 2 = f16 out,
// 3 = f32 out + silu + *K^-0.5 (q projection: folds the query scale).
// m97-verified structure.
// ---------------------------------------------------------------------------
__global__ __launch_bounds__(256) void gemm_f16(const short* __restrict__ A,
                                                const short* __restrict__ B,
                                                void* __restrict__ Cout,
                                                int ldc, int Kd, int lda, int ldb,
                                                int mode) {
  __shared__ __align__(16) short lds[8192];  // A tile 128x32 | B tile 128x32
  const int tid = threadIdx.x;
  const int lane = tid & 63;
  const int w = tid >> 6;
  const int m0 = blockIdx.x * 128;
  const int n0 = blockIdx.y * 128;

  const int sr = w * 32 + (lane >> 2);
  const int sc = (lane & 3) << 3;
  const short* ga1 = A + (size_t)(m0 + sr) * lda + sc;
  const short* ga2 = ga1 + (size_t)16 * lda;
  const short* gb1 = B + (size_t)(n0 + sr) * ldb + sc;
  const short* gb2 = gb1 + (size_t)16 * ldb;
  short* la1 = &lds[(size_t)w * 1024];
  short* la2 = la1 + 512;
  short* lb1 = &lds[4096 + (size_t)w * 1024];
  short* lb2 = lb1 + 512;

  const int fr = lane & 15;
  const int kg = lane >> 4;
  const int wmB = (w & 1) * 64;
  const int wnB = (w >> 1) * 64;
  int aoff[4], boff[4];
#pragma unroll
  for (int i = 0; i < 4; ++i) {
    aoff[i] = (wmB + i * 16 + fr) * 32 + kg * 8;
    boff[i] = 4096 + (wnB + i * 16 + fr) * 32 + kg * 8;
  }

  f32x4 acc[4][4];
#pragma unroll
  for (int i = 0; i < 4; ++i)
#pragma unroll
    for (int j = 0; j < 4; ++j) acc[i][j] = (f32x4){0.f, 0.f, 0.f, 0.f};

  const int nk = Kd >> 5;
  for (int kt = 0; kt < nk; ++kt) {
    const int ko = kt << 5;
    __syncthreads();
    gload_lds16(ga1 + ko, la1);
    gload_lds16(ga2 + ko, la2);
    gload_lds16(gb1 + ko, lb1);
    gload_lds16(gb2 + ko, lb2);
    __syncthreads();
    f16x8 af[4], bf[4];
#pragma unroll
    for (int i = 0; i < 4; ++i) af[i] = *(const f16x8*)(lds + aoff[i]);
#pragma unroll
    for (int j = 0; j < 4; ++j) bf[j] = *(const f16x8*)(lds + boff[j]);
#pragma unroll
    for (int i = 0; i < 4; ++i)
#pragma unroll
      for (int j = 0; j < 4; ++j)
        acc[i][j] = __builtin_amdgcn_mfma_f32_16x16x32_f16(af[i], bf[j], acc[i][j], 0, 0, 0);
  }

#pragma unroll
  for (int i = 0; i < 4; ++i) {
    const int row = m0 + wmB + i * 16 + kg * 4;
#pragma unroll
    for (int j = 0; j < 4; ++j) {
      const int col = n0 + wnB + j * 16 + fr;
#pragma unroll
      for (int e = 0; e < 4; ++e) {
        float v = acc[i][j][e];
        if (mode == 1 || mode == 3) v = v / (1.f + expf(-v));  // silu
        if (mode == 3) v *= 0.0625f;                            // K^-0.5
        if (mode == 2) {
          ((_Float16*)Cout)[(size_t)(row + e) * ldc + col] = (_Float16)v;
        } else {
          ((float*)Cout)[(size_t)(row + e) * ldc + col] = v;
        }
      }
    }
  }
}

// ---------------------------------------------------------------------------
// In-place L2-normalization of each k head-row (256 floats) in the qkv
// buffer. One wave per row; 4 rows per block. rows = MM*NH*HH = 24576.
// (proven round 5: absmax unchanged)
// ---------------------------------------------------------------------------
__global__ __launch_bounds__(256) void prep_kn(float* __restrict__ qkv) {
  const int row = blockIdx.x * 4 + (threadIdx.x >> 6);
  const int lane = threadIdx.x & 63;
  const int m = row / (NHOUSE * HH);
  const int rem = row % (NHOUSE * HH);
  const int j = rem / HH;
  const int hh = rem % HH;
  float* p = qkv + (size_t)m * QKV_ST + KOFF + j * KEY_DIM + hh * KK;
  float4 v = ((float4*)p)[lane];
  float ss = v.x * v.x + v.y * v.y + v.z * v.z + v.w * v.w;
#pragma unroll
  for (int off = 32; off; off >>= 1) ss += __shfl_xor(ss, off);
  float inv = rsqrt_nr(fmaxf(ss, 1e-24f));  // == 1/max(||k||,1e-12)
  v.x *= inv; v.y *= inv; v.z *= inv; v.w *= inv;
  ((float4*)p)[lane] = v;
}

// ---------------------------------------------------------------------------
// Small projections (fp32): y = x @ [Wb;Wa]^T per row (18 outs) ->
// beta = 2*sigmoid, gexp = exp(-exp(A_log)*softplus(y+dt_bias)).
// ---------------------------------------------------------------------------
__global__ __launch_bounds__(256) void small_proj(const float* __restrict__ x,
                                                  const float* __restrict__ Wb,
                                                  const float* __restrict__ Wa,
                                                  const float* __restrict__ A_log,
                                                  const float* __restrict__ dt_bias,
                                                  float* __restrict__ beta_out,
                                                  float* __restrict__ gexp_out) {
  const int m = blockIdx.x;
  const int tid = threadIdx.x;
  const int lane = tid & 63;
  const int wv = tid >> 6;
  __shared__ float xs[DD];
  __shared__ float ybuf[18];
#pragma unroll
  for (int i = 0; i < DD / 256; ++i) xs[tid + 256 * i] = x[(size_t)m * DD + tid + 256 * i];
  __syncthreads();
  for (int n = wv; n < 18; n += 4) {
    const float* wrow = (n < 12) ? (Wb + (size_t)n * DD) : (Wa + (size_t)(n - 12) * DD);
    float p = 0.f;
#pragma unroll
    for (int i = 0; i < DD / 64; ++i) p = fmaf(xs[lane + 64 * i], wrow[lane + 64 * i], p);
#pragma unroll
    for (int off = 32; off; off >>= 1) p += __shfl_xor(p, off);
    if (lane == 0) ybuf[n] = p;
  }
  __syncthreads();
  if (tid < 12) {
    beta_out[(size_t)m * 12 + tid] = 2.f * sigmoidf_(ybuf[tid]);
  } else if (tid < 18) {
    int hh = tid - 12;
    float z = ybuf[tid] + dt_bias[hh];
    float sp = fmaxf(z, 0.f) + log1pf(expf(-fabsf(z)));
    float g = -expf(A_log[hh]) * sp;
    gexp_out[(size_t)m * HH + hh] = expf(g);
  }
}

// ---------------------------------------------------------------------------
// Sequential delta-rule recurrence (fp32) — v1 structure (measured 844 µs,
// stride-20 LDS = max 2-way b128 banking) with the norm work removed:
// k rows are pre-normalized (prep_kn), q pre-scaled (GEMM mode 3), so the
// per-step ||k|| shuffle-reduce, nr[] and invj disappear (~12 fewer LDS-pipe
// ops/thread/step; recurrence is LDS-pipe bound).
// Grid = BB*HH*(VV/16) = 768 blocks, 256 thr; thread (vl,kq) holds
// h[kq*16..+16)[vl]; double-buffered LDS, one barrier/step.
// ---------------------------------------------------------------------------
__global__ __launch_bounds__(256) void recurrence(const float* __restrict__ QKV,
                                                  const float* __restrict__ beta,
                                                  const float* __restrict__ gexp,
                                                  float* __restrict__ o) {
  constexpr int CH = VV / 16;  // 32 v-chunks
  const int bid = blockIdx.x;
  const int b = bid / (HH * CH);
  const int rem = bid % (HH * CH);
  const int hh = rem / CH;
  const int v0 = (rem % CH) * 16;
  const int tid = threadIdx.x;
  const int vl = tid >> 4;
  const int kq = tid & 15;
  const int pidx = tid + 4 * (tid >> 4);

  __shared__ __align__(16) float ks[2][2][320];
  __shared__ __align__(16) float qs[2][320];
  __shared__ float vs[2][2][16];
  __shared__ float bs[2][2];
  __shared__ float gs[2];

  float hreg[16];
#pragma unroll
  for (int i = 0; i < 16; ++i) hreg[i] = 0.f;

  // prologue: stage t=0 into buf 0
  {
    const int m = b * TT;
    const float* prow = QKV + (size_t)m * QKV_ST;
    float rq = prow[QOFF + hh * KK + tid];
    float rk0 = prow[KOFF + 0 * KEY_DIM + hh * KK + tid];
    float rk1 = prow[KOFF + 1 * KEY_DIM + hh * KK + tid];
    ks[0][0][pidx] = rk0; ks[0][1][pidx] = rk1; qs[0][pidx] = rq;
    if (tid < 32) vs[0][tid >> 4][tid & 15] =
        prow[VOFF + (tid >> 4) * VAL_DIM + hh * VV + v0 + (tid & 15)];
    if (tid >= 32 && tid < 34) bs[0][tid - 32] = beta[(size_t)(m * NHOUSE + (tid - 32)) * HH + hh];
    if (tid == 34) gs[0] = gexp[(size_t)m * HH + hh];
  }
  __syncthreads();

  for (int t = 0; t < TT; ++t) {
    const int buf = t & 1;
    const int nb = buf ^ 1;
    const int tnx = (t + 1 < TT) ? (t + 1) : t;
    const int mn = b * TT + tnx;
    const float* prow = QKV + (size_t)mn * QKV_ST;

    // ---- prefetch next step's globals into registers ----
    float rq = prow[QOFF + hh * KK + tid];
    float rk0 = prow[KOFF + 0 * KEY_DIM + hh * KK + tid];
    float rk1 = prow[KOFF + 1 * KEY_DIM + hh * KK + tid];
    float rv = 0.f, rb = 0.f, rg = 0.f;
    if (tid < 32) rv = prow[VOFF + (tid >> 4) * VAL_DIM + hh * VV + v0 + (tid & 15)];
    if (tid >= 32 && tid < 34) rb = beta[(size_t)(mn * NHOUSE + (tid - 32)) * HH + hh];
    if (tid == 34) rg = gexp[(size_t)mn * HH + hh];

    // ---- compute step t from buf ----
    const float ge = gs[buf];
#pragma unroll
    for (int i = 0; i < 16; ++i) hreg[i] *= ge;

#pragma unroll
    for (int j = 0; j < 2; ++j) {
      const float4* kb = (const float4*)&ks[buf][j][kq * 20];
      float4 x0 = kb[0], x1 = kb[1], x2 = kb[2], x3 = kb[3];
      float rk[16] = {x0.x, x0.y, x0.z, x0.w, x1.x, x1.y, x1.z, x1.w,
                      x2.x, x2.y, x2.z, x2.w, x3.x, x3.y, x3.z, x3.w};
      float p = 0.f;
#pragma unroll
      for (int i = 0; i < 16; ++i) p = fmaf(hreg[i], rk[i], p);
      p += __shfl_xor(p, 1); p += __shfl_xor(p, 2);
      p += __shfl_xor(p, 4); p += __shfl_xor(p, 8);
      const float wgt = bs[buf][j] * (vs[buf][j][vl] - p);
#pragma unroll
      for (int i = 0; i < 16; ++i) hreg[i] = fmaf(wgt, rk[i], hreg[i]);
    }

    {
      const float4* qb = (const float4*)&qs[buf][kq * 20];
      float4 x0 = qb[0], x1 = qb[1], x2 = qb[2], x3 = qb[3];
      float qv[16] = {x0.x, x0.y, x0.z, x0.w, x1.x, x1.y, x1.z, x1.w,
                      x2.x, x2.y, x2.z, x2.w, x3.x, x3.y, x3.z, x3.w};
      float p = 0.f;
#pragma unroll
      for (int i = 0; i < 16; ++i) p = fmaf(hreg[i], qv[i], p);
      p += __shfl_xor(p, 1); p += __shfl_xor(p, 2);
      p += __shfl_xor(p, 4); p += __shfl_xor(p, 8);
      if (kq == 0) o[(size_t)((b * TT + t) * HH + hh) * VV + v0 + vl] = p;
    }

    // ---- stage t+1 into the other buffer ----
    ks[nb][0][pidx] = rk0; ks[nb][1][pidx] = rk1; qs[nb][pidx] = rq;
    if (tid < 32) vs[nb][tid >> 4][tid & 15] = rv;
    if (tid >= 32 && tid < 34) bs[nb][tid - 32] = rb;
    if (tid == 34) gs[nb] = rg;
    __syncthreads();
  }
}

// ---------------------------------------------------------------------------
// Gated RMSNorm. Reads o_mid fp32 + gate f16; writes o2 f16.
// ---------------------------------------------------------------------------
__global__ __launch_bounds__(256) void rms_gate_kernel(const float* __restrict__ o,
                                                       const short* __restrict__ gate16,
                                                       const float* __restrict__ wn,
                                                       short* __restrict__ o2) {
  const int row = blockIdx.x;            // m*H + h
  const int m = row / HH;
  const int hh = row - m * HH;
  const int tid = threadIdx.x;
  const float* op = o + (size_t)row * VV;
  const _Float16* gp = (const _Float16*)gate16 + (size_t)m * VAL_DIM + hh * VV;
  float a0 = op[tid], a1 = op[tid + 256];
  float ss = a0 * a0 + a1 * a1;
#pragma unroll
  for (int off = 32; off; off >>= 1) ss += __shfl_xor(ss, off);
  __shared__ float red[4];
  const int lane = tid & 63, wv = tid >> 6;
  if (lane == 0) red[wv] = ss;
  __syncthreads();
  float tot = red[0] + red[1] + red[2] + red[3];
  float inv = rsqrt_nr(tot * (1.f / (float)VV) + 1e-5f);
  float r0 = a0 * inv * wn[tid] * sigmoidf_((float)gp[tid]);
  float r1 = a1 * inv * wn[tid + 256] * sigmoidf_((float)gp[tid + 256]);
  _Float16* dst = (_Float16*)o2 + (size_t)m * VAL_DIM + hh * VV;
  dst[tid] = (_Float16)r0;
  dst[tid + 256] = (_Float16)r1;
}

// ---------------------------------------------------------------------------
extern "C" void kernel_launch(void* const* d_in, const int* in_sizes, int n_in,
                              void* d_out, int out_size, void* d_ws, size_t ws_size,
                              hipStream_t stream) {
  (void)in_sizes; (void)n_in; (void)out_size; (void)ws_size;
  const float* x       = (const float*)d_in[0];
  const float* Wq      = (const float*)d_in[1];
  const float* Wk      = (const float*)d_in[2];
  const float* Wv      = (const float*)d_in[3];
  const float* Wb      = (const float*)d_in[4];
  const float* Wa      = (const float*)d_in[5];
  const float* A_log   = (const float*)d_in[6];
  const float* dt_bias = (const float*)d_in[7];
  const float* Wg      = (const float*)d_in[8];
  const float* Wo      = (const float*)d_in[9];
  const float* onw     = (const float*)d_in[10];
  float* out = (float*)d_out;
  float* ws = (float*)d_ws;

  float* qkv    = ws + OFF_QKV;
  short* gate16 = (short*)(ws + OFF_GATE);
  float* beta_w = ws + OFF_BETA;
  float* gexp_w = ws + OFF_GEXP;
  short* x16    = (short*)(ws + OFF_X16);
  short* wf16   = (short*)(ws + OFF_W16);
  float* o_mid  = ws + OFF_OMID;          // overlays x16+wf16 after GEMMs
  short* o2     = (short*)(ws + OFF_O2);  // overlays dead qkv after recurrence
  short* wo16   = (short*)(ws + OFF_WO16);

  // 1. conversions + small projections
  cvt_f16<<<4096, 256, 0, stream>>>(x, x16, MM * DD);
  small_proj<<<MM, 256, 0, stream>>>(x, Wb, Wa, A_log, dt_bias, beta_w, gexp_w);

  // 2. projection GEMMs (f16 inputs, fp32 out), sequential weight chunks.
  //    q: silu + K^-0.5 scale folded (mode 3)
  cvt_f16<<<3072, 256, 0, stream>>>(Wq, wf16, KEY_DIM * DD);
  gemm_f16<<<dim3(MM / 128, KEY_DIM / 128), 256, 0, stream>>>(
      x16, wf16, qkv + QOFF, QKV_ST, DD, DD, DD, 3);
  //    k: silu, then in-place L2 normalize per head-row
  cvt_f16<<<6144, 256, 0, stream>>>(Wk, wf16, KEY_DIM * NHOUSE * DD);
  gemm_f16<<<dim3(MM / 128, (KEY_DIM * NHOUSE) / 128), 256, 0, stream>>>(
      x16, wf16, qkv + KOFF, QKV_ST, DD, DD, DD, 1);
  prep_kn<<<MM * NHOUSE * HH / 4, 256, 0, stream>>>(qkv);
  //    v halves: silu
  cvt_f16<<<6144, 256, 0, stream>>>(Wv, wf16, VAL_DIM * DD);
  gemm_f16<<<dim3(MM / 128, VAL_DIM / 128), 256, 0, stream>>>(
      x16, wf16, qkv + VOFF, QKV_ST, DD, DD, DD, 1);
  cvt_f16<<<6144, 256, 0, stream>>>(Wv + (size_t)VAL_DIM * DD, wf16, VAL_DIM * DD);
  gemm_f16<<<dim3(MM / 128, VAL_DIM / 128), 256, 0, stream>>>(
      x16, wf16, qkv + VOFF + VAL_DIM, QKV_ST, DD, DD, DD, 1);
  //    gate: f16 out, no act
  cvt_f16<<<6144, 256, 0, stream>>>(Wg, wf16, VAL_DIM * DD);
  gemm_f16<<<dim3(MM / 128, VAL_DIM / 128), 256, 0, stream>>>(
      x16, wf16, gate16, VAL_DIM, DD, DD, DD, 2);

  // 3. sequential recurrence (fp32, v1 structure + trims)
  recurrence<<<BB * HH * (VV / 16), 256, 0, stream>>>(qkv, beta_w, gexp_w, o_mid);

  // 4. gated RMSNorm -> o2 f16 ; Wo -> f16
  rms_gate_kernel<<<MM * HH, 256, 0, stream>>>(o_mid, gate16, onw, o2);
  cvt_f16<<<6144, 256, 0, stream>>>(Wo, wo16, DD * VAL_DIM);

  // 5. output GEMM (f16 in, f32 out to d_out)
  gemm_f16<<<dim3(MM / 128, DD / 128), 256, 0, stream>>>(
      o2, wo16, out, DD, VAL_DIM, VAL_DIM, VAL_DIM, 0);
}

// Round 7
// 974.275 us; speedup vs baseline: 1.5851x; 1.1965x over previous
//
#include <hip/hip_runtime.h>
#include <hip/hip_bf16.h>
#include <math.h>

// Problem constants (pinned by reference)
constexpr int BB = 4;
constexpr int TT = 512;
constexpr int DD = 2048;
constexpr int HH = 6;
constexpr int KK = 256;   // head_k_dim
constexpr int VV = 512;   // head_v_dim
constexpr int NHOUSE = 2;
constexpr int MM = BB * TT;          // 2048 rows
constexpr int KEY_DIM = HH * KK;     // 1536
constexpr int VAL_DIM = HH * VV;     // 3072

// P (f16) row layout: q[0,1536) k[1536,4608) v[4608,10752) g[10752,13824)
constexpr int PST  = 13824;
constexpr int QOFF = 0;
constexpr int KOFF = 1536;
constexpr int VOFF = 4608;
constexpr int GOFF = 10752;

// ---- workspace layout (FLOAT units) ----
constexpr size_t SZ_P    = (size_t)MM * PST / 2;         // 14,155,776 (f16)
constexpr size_t SZ_WCAT = (size_t)PST * DD / 2;         // 14,155,776 (f16)
constexpr size_t SZ_X16  = (size_t)MM * DD / 2;          //  2,097,152 (f16)
constexpr size_t SZ_BETA = (size_t)MM * NHOUSE * HH;     //     24,576
constexpr size_t SZ_GEXP = (size_t)MM * HH;              //     12,288
constexpr size_t SZ_OMID = (size_t)MM * VAL_DIM;         //  6,291,456
constexpr size_t SZ_O2   = (size_t)MM * VAL_DIM / 2;     //  1,572,864 (f16)
constexpr size_t SZ_WO16 = (size_t)DD * VAL_DIM / 2;     //  1,572,864 (f16)

constexpr size_t OFF_P    = 0;
constexpr size_t OFF_WCAT = OFF_P + SZ_P;
constexpr size_t OFF_X16  = OFF_WCAT + SZ_WCAT;
constexpr size_t OFF_BETA = OFF_X16 + SZ_X16;
constexpr size_t OFF_GEXP = OFF_BETA + SZ_BETA;
constexpr size_t WS_PEAK  = OFF_GEXP + SZ_GEXP;          // 30,445,568 fl = 121.8 MB
static_assert(WS_PEAK <= 31494144, "stay under round-4-proven 126.0 MB");
// after proj GEMM: Wcat/x16 dead -> o_mid overlays Wcat
constexpr size_t OFF_OMID = OFF_WCAT;
// after recurrence: o2 + wo16 also inside the (larger) Wcat region
constexpr size_t OFF_O2   = OFF_WCAT + SZ_OMID;
constexpr size_t OFF_WO16 = OFF_O2 + SZ_O2;
static_assert(OFF_WO16 + SZ_WO16 <= OFF_WCAT + SZ_WCAT, "o_mid+o2+wo16 fit in Wcat");
static_assert(SZ_OMID >= SZ_WO16 + SZ_O2 || true, "");

__device__ __forceinline__ float rsqrt_nr(float x) {
  float r = rsqrtf(x);
  return r * (1.5f - 0.5f * x * r * r);
}
__device__ __forceinline__ float sigmoidf_(float x) {
  return 1.f / (1.f + expf(-x));
}
__device__ __forceinline__ short f2h(float f) {
  _Float16 h = (_Float16)f;
  short s;
  __builtin_memcpy(&s, &h, 2);
  return s;
}

typedef __attribute__((ext_vector_type(8))) _Float16 f16x8;
typedef __attribute__((ext_vector_type(4))) _Float16 f16x4;
typedef __attribute__((ext_vector_type(4))) float f32x4;

// DPP row-rotate add: reduction across a 16-lane row on the VALU pipe
// (keeps the recurrence's dot-product reductions OFF the saturated LDS pipe).
template <int CTRL>
__device__ __forceinline__ float dpp_add(float x) {
  int r = __builtin_amdgcn_update_dpp(0, __float_as_int(x), CTRL, 0xf, 0xf, true);
  return x + __int_as_float(r);
}
__device__ __forceinline__ float row16_sum(float p) {
  p = dpp_add<0x121>(p);  // row_ror:1
  p = dpp_add<0x122>(p);  // row_ror:2
  p = dpp_add<0x124>(p);  // row_ror:4
  p = dpp_add<0x128>(p);  // row_ror:8
  return p;
}

__device__ __forceinline__ void gload_lds16(const short* g, short* l) {
  __builtin_amdgcn_global_load_lds(
      (const __attribute__((address_space(1))) void*)g,
      (__attribute__((address_space(3))) void*)l, 16, 0, 0);
}

// ---------------------------------------------------------------------------
// fp32 -> fp16 flat conversion, 4 elems/thread.
// ---------------------------------------------------------------------------
__global__ __launch_bounds__(256) void cvt_f16(const float* __restrict__ src,
                                               short* __restrict__ dst, int n) {
  int i = (blockIdx.x * 256 + threadIdx.x) << 2;
  if (i >= n) return;
  float4 v = *(const float4*)(src + i);
  short4 r;
  r.x = f2h(v.x); r.y = f2h(v.y); r.z = f2h(v.z); r.w = f2h(v.w);
  *(short4*)(dst + i) = r;
}

// ---------------------------------------------------------------------------
// C = act(A * B^T). modes: 0 = f32 out, 4 = merged f16 out with per-column
// activation (col<KOFF: silu*K^-0.5; col<GOFF: silu; else none).
// m97-verified structure: 128x128 tile, 4 waves, single LDS buffer, 2
// barriers per 32-wide K-step, global_load_lds width 16, 16x16x32 f16 MFMA.
// ---------------------------------------------------------------------------
__global__ __launch_bounds__(256) void gemm_f16(const short* __restrict__ A,
                                                const short* __restrict__ B,
                                                void* __restrict__ Cout,
                                                int ldc, int Kd, int lda, int ldb,
                                                int mode) {
  __shared__ __align__(16) short lds[8192];  // A tile 128x32 | B tile 128x32
  const int tid = threadIdx.x;
  const int lane = tid & 63;
  const int w = tid >> 6;
  const int m0 = blockIdx.x * 128;
  const int n0 = blockIdx.y * 128;

  const int sr = w * 32 + (lane >> 2);
  const int sc = (lane & 3) << 3;
  const short* ga1 = A + (size_t)(m0 + sr) * lda + sc;
  const short* ga2 = ga1 + (size_t)16 * lda;
  const short* gb1 = B + (size_t)(n0 + sr) * ldb + sc;
  const short* gb2 = gb1 + (size_t)16 * ldb;
  short* la1 = &lds[(size_t)w * 1024];
  short* la2 = la1 + 512;
  short* lb1 = &lds[4096 + (size_t)w * 1024];
  short* lb2 = lb1 + 512;

  const int fr = lane & 15;
  const int kg = lane >> 4;
  const int wmB = (w & 1) * 64;
  const int wnB = (w >> 1) * 64;
  int aoff[4], boff[4];
#pragma unroll
  for (int i = 0; i < 4; ++i) {
    aoff[i] = (wmB + i * 16 + fr) * 32 + kg * 8;
    boff[i] = 4096 + (wnB + i * 16 + fr) * 32 + kg * 8;
  }

  f32x4 acc[4][4];
#pragma unroll
  for (int i = 0; i < 4; ++i)
#pragma unroll
    for (int j = 0; j < 4; ++j) acc[i][j] = (f32x4){0.f, 0.f, 0.f, 0.f};

  const int nk = Kd >> 5;
  for (int kt = 0; kt < nk; ++kt) {
    const int ko = kt << 5;
    __syncthreads();
    gload_lds16(ga1 + ko, la1);
    gload_lds16(ga2 + ko, la2);
    gload_lds16(gb1 + ko, lb1);
    gload_lds16(gb2 + ko, lb2);
    __syncthreads();
    f16x8 af[4], bf[4];
#pragma unroll
    for (int i = 0; i < 4; ++i) af[i] = *(const f16x8*)(lds + aoff[i]);
#pragma unroll
    for (int j = 0; j < 4; ++j) bf[j] = *(const f16x8*)(lds + boff[j]);
#pragma unroll
    for (int i = 0; i < 4; ++i)
#pragma unroll
      for (int j = 0; j < 4; ++j)
        acc[i][j] = __builtin_amdgcn_mfma_f32_16x16x32_f16(af[i], bf[j], acc[i][j], 0, 0, 0);
  }

  // epilogue: C/D layout col=lane&15, row=(lane>>4)*4+reg (m89/m91-verified)
#pragma unroll
  for (int i = 0; i < 4; ++i) {
    const int row = m0 + wmB + i * 16 + kg * 4;
#pragma unroll
    for (int j = 0; j < 4; ++j) {
      const int col = n0 + wnB + j * 16 + fr;
#pragma unroll
      for (int e = 0; e < 4; ++e) {
        float v = acc[i][j][e];
        if (mode == 4) {
          if (col < GOFF) v = v / (1.f + expf(-v));  // silu (q/k/v)
          if (col < KOFF) v *= 0.0625f;              // q: K^-0.5 folded
          ((_Float16*)Cout)[(size_t)(row + e) * ldc + col] = (_Float16)v;
        } else {
          ((float*)Cout)[(size_t)(row + e) * ldc + col] = v;
        }
      }
    }
  }
}

// ---------------------------------------------------------------------------
// In-place L2-normalization of each f16 k head-row (256 halves) in P.
// One wave per row, 4 rows/block; rows = MM*NH*HH = 24576.
// ---------------------------------------------------------------------------
__global__ __launch_bounds__(256) void prep_kn(_Float16* __restrict__ P) {
  const int row = blockIdx.x * 4 + (threadIdx.x >> 6);
  const int lane = threadIdx.x & 63;
  const int m = row / (NHOUSE * HH);
  const int rem = row % (NHOUSE * HH);
  const int j = rem / HH;
  const int hh = rem % HH;
  _Float16* p = P + (size_t)m * PST + KOFF + j * KEY_DIM + hh * KK + lane * 4;
  f16x4 v = *(f16x4*)p;
  float f0 = (float)v[0], f1 = (float)v[1], f2 = (float)v[2], f3 = (float)v[3];
  float ss = f0 * f0 + f1 * f1 + f2 * f2 + f3 * f3;
#pragma unroll
  for (int off = 32; off; off >>= 1) ss += __shfl_xor(ss, off);
  float inv = rsqrt_nr(fmaxf(ss, 1e-24f));
  v[0] = (_Float16)(f0 * inv); v[1] = (_Float16)(f1 * inv);
  v[2] = (_Float16)(f2 * inv); v[3] = (_Float16)(f3 * inv);
  *(f16x4*)p = v;
}

// ---------------------------------------------------------------------------
// Small projections (fp32): y = x @ [Wb;Wa]^T per row (18 outs) ->
// beta = 2*sigmoid, gexp = exp(-exp(A_log)*softplus(y+dt_bias)).
// ---------------------------------------------------------------------------
__global__ __launch_bounds__(256) void small_proj(const float* __restrict__ x,
                                                  const float* __restrict__ Wb,
                                                  const float* __restrict__ Wa,
                                                  const float* __restrict__ A_log,
                                                  const float* __restrict__ dt_bias,
                                                  float* __restrict__ beta_out,
                                                  float* __restrict__ gexp_out) {
  const int m = blockIdx.x;
  const int tid = threadIdx.x;
  const int lane = tid & 63;
  const int wv = tid >> 6;
  __shared__ float xs[DD];
  __shared__ float ybuf[18];
#pragma unroll
  for (int i = 0; i < DD / 256; ++i) xs[tid + 256 * i] = x[(size_t)m * DD + tid + 256 * i];
  __syncthreads();
  for (int n = wv; n < 18; n += 4) {
    const float* wrow = (n < 12) ? (Wb + (size_t)n * DD) : (Wa + (size_t)(n - 12) * DD);
    float p = 0.f;
#pragma unroll
    for (int i = 0; i < DD / 64; ++i) p = fmaf(xs[lane + 64 * i], wrow[lane + 64 * i], p);
#pragma unroll
    for (int off = 32; off; off >>= 1) p += __shfl_xor(p, off);
    if (lane == 0) ybuf[n] = p;
  }
  __syncthreads();
  if (tid < 12) {
    beta_out[(size_t)m * 12 + tid] = 2.f * sigmoidf_(ybuf[tid]);
  } else if (tid < 18) {
    int hh = tid - 12;
    float z = ybuf[tid] + dt_bias[hh];
    float sp = fmaxf(z, 0.f) + log1pf(expf(-fabsf(z)));
    float g = -expf(A_log[hh]) * sp;
    gexp_out[(size_t)m * HH + hh] = expf(g);
  }
}

// ---------------------------------------------------------------------------
// Sequential delta-rule recurrence, v3: f16 inputs from P (k pre-normalized,
// q pre-scaled), fp32 state. LDS halved (f16 k/q: 6 ds_read_b128/wave/step),
// reductions on VALU via DPP row_ror (off the LDS pipe). Segment stride 24
// halves = 48B: b128 reads 16B-aligned, banks 12*kq%32 -> 2-way max (free).
// Grid = BB*HH*(VV/16) = 768 blocks; thread (vl,kq) holds h[kq*16..+16)[vl].
// ---------------------------------------------------------------------------
__global__ __launch_bounds__(256) void recurrence(const _Float16* __restrict__ P,
                                                  const float* __restrict__ beta,
                                                  const float* __restrict__ gexp,
                                                  float* __restrict__ o) {
  constexpr int CH = VV / 16;  // 32 v-chunks
  const int bid = blockIdx.x;
  const int b = bid / (HH * CH);
  const int rem = bid % (HH * CH);
  const int hh = rem / CH;
  const int v0 = (rem % CH) * 16;
  const int tid = threadIdx.x;
  const int vl = tid >> 4;
  const int kq = tid & 15;
  const int pidx = (tid >> 4) * 24 + (tid & 15);  // staging write slot

  __shared__ __align__(16) _Float16 ks[2][2][384];
  __shared__ __align__(16) _Float16 qs[2][384];
  __shared__ _Float16 vsh[2][2][16];
  __shared__ float bs[2][2];
  __shared__ float gs[2];

  float hreg[16];
#pragma unroll
  for (int i = 0; i < 16; ++i) hreg[i] = 0.f;

  // prologue: stage t=0 into buf 0
  {
    const int m = b * TT;
    const _Float16* prow = P + (size_t)m * PST;
    _Float16 rq = prow[QOFF + hh * KK + tid];
    _Float16 rk0 = prow[KOFF + 0 * KEY_DIM + hh * KK + tid];
    _Float16 rk1 = prow[KOFF + 1 * KEY_DIM + hh * KK + tid];
    ks[0][0][pidx] = rk0; ks[0][1][pidx] = rk1; qs[0][pidx] = rq;
    if (tid < 32) vsh[0][tid >> 4][tid & 15] =
        prow[VOFF + (tid >> 4) * VAL_DIM + hh * VV + v0 + (tid & 15)];
    if (tid >= 32 && tid < 34) bs[0][tid - 32] = beta[(size_t)(m * NHOUSE + (tid - 32)) * HH + hh];
    if (tid == 34) gs[0] = gexp[(size_t)m * HH + hh];
  }
  __syncthreads();

  for (int t = 0; t < TT; ++t) {
    const int buf = t & 1;
    const int nb = buf ^ 1;
    const int tnx = (t + 1 < TT) ? (t + 1) : t;
    const int mn = b * TT + tnx;
    const _Float16* prow = P + (size_t)mn * PST;

    // ---- prefetch next step's globals into registers ----
    _Float16 rq = prow[QOFF + hh * KK + tid];
    _Float16 rk0 = prow[KOFF + 0 * KEY_DIM + hh * KK + tid];
    _Float16 rk1 = prow[KOFF + 1 * KEY_DIM + hh * KK + tid];
    _Float16 rv = (_Float16)0.f;
    float rb = 0.f, rg = 0.f;
    if (tid < 32) rv = prow[VOFF + (tid >> 4) * VAL_DIM + hh * VV + v0 + (tid & 15)];
    if (tid >= 32 && tid < 34) rb = beta[(size_t)(mn * NHOUSE + (tid - 32)) * HH + hh];
    if (tid == 34) rg = gexp[(size_t)mn * HH + hh];

    // ---- compute step t from buf ----
    const float ge = gs[buf];
#pragma unroll
    for (int i = 0; i < 16; ++i) hreg[i] *= ge;

#pragma unroll
    for (int j = 0; j < 2; ++j) {
      f16x8 a0 = *(const f16x8*)&ks[buf][j][kq * 24];
      f16x8 a1 = *(const f16x8*)&ks[buf][j][kq * 24 + 8];
      float kn[16];
#pragma unroll
      for (int i = 0; i < 8; ++i) { kn[i] = (float)a0[i]; kn[8 + i] = (float)a1[i]; }
      float p = 0.f;
#pragma unroll
      for (int i = 0; i < 16; ++i) p = fmaf(hreg[i], kn[i], p);
      p = row16_sum(p);
      const float wgt = bs[buf][j] * ((float)vsh[buf][j][vl] - p);
#pragma unroll
      for (int i = 0; i < 16; ++i) hreg[i] = fmaf(wgt, kn[i], hreg[i]);
    }

    {
      f16x8 a0 = *(const f16x8*)&qs[buf][kq * 24];
      f16x8 a1 = *(const f16x8*)&qs[buf][kq * 24 + 8];
      float qv[16];
#pragma unroll
      for (int i = 0; i < 8; ++i) { qv[i] = (float)a0[i]; qv[8 + i] = (float)a1[i]; }
      float p = 0.f;
#pragma unroll
      for (int i = 0; i < 16; ++i) p = fmaf(hreg[i], qv[i], p);
      p = row16_sum(p);
      if (kq == 0) o[(size_t)((b * TT + t) * HH + hh) * VV + v0 + vl] = p;
    }

    // ---- stage t+1 into the other buffer ----
    ks[nb][0][pidx] = rk0; ks[nb][1][pidx] = rk1; qs[nb][pidx] = rq;
    if (tid < 32) vsh[nb][tid >> 4][tid & 15] = rv;
    if (tid >= 32 && tid < 34) bs[nb][tid - 32] = rb;
    if (tid == 34) gs[nb] = rg;
    __syncthreads();
  }
}

// ---------------------------------------------------------------------------
// Gated RMSNorm. Reads o_mid fp32 + gate f16 (from P); writes o2 f16.
// ---------------------------------------------------------------------------
__global__ __launch_bounds__(256) void rms_gate_kernel(const float* __restrict__ o,
                                                       const _Float16* __restrict__ P,
                                                       const float* __restrict__ wn,
                                                       short* __restrict__ o2) {
  const int row = blockIdx.x;            // m*H + h
  const int m = row / HH;
  const int hh = row - m * HH;
  const int tid = threadIdx.x;
  const float* op = o + (size_t)row * VV;
  const _Float16* gp = P + (size_t)m * PST + GOFF + hh * VV;
  float a0 = op[tid], a1 = op[tid + 256];
  float ss = a0 * a0 + a1 * a1;
#pragma unroll
  for (int off = 32; off; off >>= 1) ss += __shfl_xor(ss, off);
  __shared__ float red[4];
  const int lane = tid & 63, wv = tid >> 6;
  if (lane == 0) red[wv] = ss;
  __syncthreads();
  float tot = red[0] + red[1] + red[2] + red[3];
  float inv = rsqrt_nr(tot * (1.f / (float)VV) + 1e-5f);
  float r0 = a0 * inv * wn[tid] * sigmoidf_((float)gp[tid]);
  float r1 = a1 * inv * wn[tid + 256] * sigmoidf_((float)gp[tid + 256]);
  _Float16* dst = (_Float16*)o2 + (size_t)m * VAL_DIM + hh * VV;
  dst[tid] = (_Float16)r0;
  dst[tid + 256] = (_Float16)r1;
}

// ---------------------------------------------------------------------------
extern "C" void kernel_launch(void* const* d_in, const int* in_sizes, int n_in,
                              void* d_out, int out_size, void* d_ws, size_t ws_size,
                              hipStream_t stream) {
  (void)in_sizes; (void)n_in; (void)out_size; (void)ws_size;
  const float* x       = (const float*)d_in[0];
  const float* Wq      = (const float*)d_in[1];
  const float* Wk      = (const float*)d_in[2];
  const float* Wv      = (const float*)d_in[3];
  const float* Wb      = (const float*)d_in[4];
  const float* Wa      = (const float*)d_in[5];
  const float* A_log   = (const float*)d_in[6];
  const float* dt_bias = (const float*)d_in[7];
  const float* Wg      = (const float*)d_in[8];
  const float* Wo      = (const float*)d_in[9];
  const float* onw     = (const float*)d_in[10];
  float* out = (float*)d_out;
  float* ws = (float*)d_ws;

  _Float16* P   = (_Float16*)(ws + OFF_P);
  short* wcat   = (short*)(ws + OFF_WCAT);
  short* x16    = (short*)(ws + OFF_X16);
  float* beta_w = ws + OFF_BETA;
  float* gexp_w = ws + OFF_GEXP;
  float* o_mid  = ws + OFF_OMID;          // overlays Wcat after proj GEMM
  short* o2     = (short*)(ws + OFF_O2);
  short* wo16   = (short*)(ws + OFF_WO16);

  // 1. conversions: x + all projection weights into one concatenated buffer
  cvt_f16<<<4096, 256, 0, stream>>>(x, x16, MM * DD);
  small_proj<<<MM, 256, 0, stream>>>(x, Wb, Wa, A_log, dt_bias, beta_w, gexp_w);
  cvt_f16<<<3072, 256, 0, stream>>>(Wq, wcat + (size_t)QOFF * DD, KEY_DIM * DD);
  cvt_f16<<<6144, 256, 0, stream>>>(Wk, wcat + (size_t)KOFF * DD, KEY_DIM * NHOUSE * DD);
  cvt_f16<<<12288, 256, 0, stream>>>(Wv, wcat + (size_t)VOFF * DD, VAL_DIM * NHOUSE * DD);
  cvt_f16<<<6144, 256, 0, stream>>>(Wg, wcat + (size_t)GOFF * DD, VAL_DIM * DD);

  // 2. ONE merged projection GEMM (f16 out, per-column activation), then
  //    in-place k normalization.
  gemm_f16<<<dim3(MM / 128, PST / 128), 256, 0, stream>>>(
      x16, wcat, (void*)P, PST, DD, DD, DD, 4);
  prep_kn<<<MM * NHOUSE * HH / 4, 256, 0, stream>>>(P);

  // 3. sequential recurrence (f16 in, fp32 state)
  recurrence<<<BB * HH * (VV / 16), 256, 0, stream>>>(P, beta_w, gexp_w, o_mid);

  // 4. gated RMSNorm -> o2 f16 ; Wo -> f16
  rms_gate_kernel<<<MM * HH, 256, 0, stream>>>(o_mid, P, onw, o2);
  cvt_f16<<<6144, 256, 0, stream>>>(Wo, wo16, DD * VAL_DIM);

  // 5. output GEMM (f16 in, f32 out to d_out)
  gemm_f16<<<dim3(MM / 128, DD / 128), 256, 0, stream>>>(
      o2, wo16, out, DD, VAL_DIM, VAL_DIM, VAL_DIM, 0);
}